// Round 3
// baseline (92.049 us; speedup 1.0000x reference)
//
#include <hip/hip_runtime.h>

// GraphEmbeddings interaction network — fp16 MFMA version, fused launches.
// B=64, P=128, F=16. Per (b, receiver p) block: senders processed in 2 chunks
// of 64 rows; fr1 (96->64) and fr2 (64->32) via mfma_f32_16x16x32_f16, fp32
// accumulation; fo MLP fused as a 1-wave tail (agg complete in-LDS).
// fr0 factors through nodes: Rc = (x@W0r)*s0+c0, Sc = (x@W0s)*s0, stored fp16.

#define NB 64
#define NF 16
#define NP 128

typedef _Float16 f16x8 __attribute__((ext_vector_type(8)));
typedef _Float16 f16x2 __attribute__((ext_vector_type(2)));
typedef float    f32x4 __attribute__((ext_vector_type(4)));

// ---------------- prep: fold BN + pack W1/W2 fragments (one launch) ----------
__device__ __forceinline__ void fold1(int t, int n, const float* b, const float* g,
                                      const float* beta, const float* mu, const float* var,
                                      float* s_out, float* c_out) {
    if (t < n) {
        float s = g[t] * rsqrtf(var[t] + 1e-3f);
        s_out[t] = s;
        c_out[t] = (b[t] - mu[t]) * s + beta[t];
    }
}

__global__ void prep_kernel(const float* w1, const float* w2,
                            _Float16* w1f, _Float16* w2f, float* cs,
    const float* b0, const float* g0, const float* be0, const float* m0, const float* v0,
    const float* b1, const float* g1, const float* be1, const float* m1, const float* v1,
    const float* b2, const float* g2, const float* be2, const float* m2, const float* v2,
    const float* b3, const float* g3, const float* be3, const float* m3, const float* v3,
    const float* b4, const float* g4, const float* be4, const float* m4, const float* v4) {
    int t = threadIdx.x;
    if (blockIdx.x == 0) {
        fold1(t, 96, b0, g0, be0, m0, v0, cs + 0,   cs + 96);
        fold1(t, 64, b1, g1, be1, m1, v1, cs + 192, cs + 256);
        fold1(t, 32, b2, g2, be2, m2, v2, cs + 320, cs + 352);
        fold1(t, 64, b3, g3, be3, m3, v3, cs + 384, cs + 448);
        fold1(t, 32, b4, g4, be4, m4, v4, cs + 512, cs + 544);
    } else {
        int i = (blockIdx.x - 1) * 256 + t;   // 0..8191
        if (i < 6144) {                       // w1f[kb][n][j] = W1[kb*8+j][n]
            int j = i & 7, n = (i >> 3) & 63, kb = i >> 9;
            w1f[i] = (_Float16)w1[(kb * 8 + j) * 64 + n];
        } else {                              // w2f[kb][n][j] = W2[kb*8+j][n]
            int i2 = i - 6144;
            int j = i2 & 7, n = (i2 >> 3) & 31, kb = i2 >> 8;
            w2f[i2] = (_Float16)w2[(kb * 8 + j) * 32 + n];
        }
    }
}

// ---------------- per-node first-layer partials (BN0 folded), fp16 out ------
__global__ void rs_kernel(const float* __restrict__ x, const float* __restrict__ w0,
                          const float* __restrict__ cs,
                          _Float16* __restrict__ Rch, _Float16* __restrict__ Sch) {
    int idx = blockIdx.x * blockDim.x + threadIdx.x;   // B*P*48 (2 ch per thread)
    if (idx >= NB * NP * 48) return;
    int c2 = idx % 48;
    int node = idx / 48;
    int p = node & (NP - 1);
    int b = node >> 7;
    const float* xb = x + b * NF * NP + p;
    float r0 = 0.f, r1 = 0.f, s0 = 0.f, s1 = 0.f;
#pragma unroll
    for (int f = 0; f < NF; ++f) {
        float xv = xb[f * NP];
        float2 wr = *(const float2*)&w0[f * 96 + c2 * 2];
        float2 ws = *(const float2*)&w0[(NF + f) * 96 + c2 * 2];
        r0 += xv * wr.x; r1 += xv * wr.y;
        s0 += xv * ws.x; s1 += xv * ws.y;
    }
    float sa = cs[c2 * 2], sb = cs[c2 * 2 + 1];
    float ca = cs[96 + c2 * 2], cb = cs[96 + c2 * 2 + 1];
    f16x2 rv; rv[0] = (_Float16)(r0 * sa + ca); rv[1] = (_Float16)(r1 * sb + cb);
    f16x2 sv; sv[0] = (_Float16)(s0 * sa);      sv[1] = (_Float16)(s1 * sb);
    *(f16x2*)&Rch[idx * 2] = rv;
    *(f16x2*)&Sch[idx * 2] = sv;
}

// ---------------- edge MLP via MFMA + fused fo tail (the hot kernel) --------
// Block = (b, p). 256 threads = 4 waves. 2 chunks of 64 sender rows.
// Wave w owns rows [16w,16w+16) of the chunk. E1 stride 104 fp16 (208B),
// E2 stride 80 fp16 (160B) — both 16B-aligned rows.
__global__ __launch_bounds__(256) void edge_mlp_mfma(
    const _Float16* __restrict__ Rch, const _Float16* __restrict__ Sch,
    const _Float16* __restrict__ w1f, const _Float16* __restrict__ w2f,
    const float* __restrict__ cs, const float* __restrict__ x,
    const float* __restrict__ fo0w, const float* __restrict__ fo1w,
    float* __restrict__ fo_out)
{
    __shared__ _Float16 E1[64 * 104];
    __shared__ _Float16 E2[64 * 80];
    __shared__ _Float16 Rcl[96];
    __shared__ float red[128];
    __shared__ float hbuf[48];
    __shared__ float h2[64];

    const int tid = threadIdx.x;
    const int blk = blockIdx.x;        // b*128 + p
    const int b   = blk >> 7;
    const int p   = blk & 127;
    const int lane = tid & 63;
    const int w    = tid >> 6;
    const int g    = lane >> 4;
    const int l15  = lane & 15;

    // B-fragments of W1/W2 in registers
    const f16x8* W1v = (const f16x8*)w1f;
    const f16x8* W2v = (const f16x8*)w2f;
    f16x8 bw1[3][4];
#pragma unroll
    for (int ks = 0; ks < 3; ++ks)
#pragma unroll
        for (int nt = 0; nt < 4; ++nt)
            bw1[ks][nt] = W1v[(ks * 4 + g) * 64 + nt * 16 + l15];
    f16x8 bw2[2][2];
#pragma unroll
    for (int ks = 0; ks < 2; ++ks)
#pragma unroll
        for (int nt = 0; nt < 2; ++nt)
            bw2[ks][nt] = W2v[(ks * 4 + g) * 32 + nt * 16 + l15];

    float s1v[4], c1v[4];
#pragma unroll
    for (int nt = 0; nt < 4; ++nt) {
        s1v[nt] = cs[192 + nt * 16 + l15];
        c1v[nt] = cs[256 + nt * 16 + l15];
    }
    float s2v[2], c2v[2];
#pragma unroll
    for (int nt = 0; nt < 2; ++nt) {
        s2v[nt] = cs[320 + nt * 16 + l15];
        c2v[nt] = cs[352 + nt * 16 + l15];
    }

    if (tid < 96) Rcl[tid] = Rch[(size_t)blk * 96 + tid];
    __syncthreads();

    float sum0 = 0.f, sum1 = 0.f;

#pragma unroll
    for (int chunk = 0; chunk < 2; ++chunk) {
        // ---- Phase A: E1[r][ch] = relu(Rc[ch] + Sc[64*chunk+r][ch]), fp16 pk ops
        const f16x8* Sb = (const f16x8*)(Sch + ((size_t)b * NP + chunk * 64) * 96);
#pragma unroll
        for (int it = 0; it < 3; ++it) {
            int idx = tid + it * 256;            // 0..767 (64 rows x 12)
            int row = idx / 12;
            int c8  = idx - row * 12;
            f16x8 sv = Sb[idx];
            f16x8 rv = *(const f16x8*)&Rcl[c8 * 8];
            f16x8 o = sv + rv;
            f16x8 zz = {};
            o = __builtin_elementwise_max(o, zz);
            *(f16x8*)&E1[row * 104 + c8 * 8] = o;
        }
        __syncthreads();

        // ---- fr1: C1[64x64] = E1 @ W1 ----
        f32x4 acc[4];
#pragma unroll
        for (int nt = 0; nt < 4; ++nt) acc[nt] = (f32x4){0.f, 0.f, 0.f, 0.f};
#pragma unroll
        for (int ks = 0; ks < 3; ++ks) {
            f16x8 af = *(const f16x8*)&E1[(16 * w + l15) * 104 + ks * 32 + g * 8];
#pragma unroll
            for (int nt = 0; nt < 4; ++nt)
                acc[nt] = __builtin_amdgcn_mfma_f32_16x16x32_f16(af, bw1[ks][nt], acc[nt], 0, 0, 0);
        }

        // ---- epilogue 1: E2 = relu(C1*s1+c1) -> fp16 (wave-private rows) ----
#pragma unroll
        for (int nt = 0; nt < 4; ++nt)
#pragma unroll
            for (int r = 0; r < 4; ++r) {
                int row = 16 * w + 4 * g + r;
                E2[row * 80 + nt * 16 + l15] =
                    (_Float16)fmaxf(acc[nt][r] * s1v[nt] + c1v[nt], 0.f);
            }
        __syncthreads();

        // ---- fr2: C2[64x32] = E2 @ W2 ----
        f32x4 acc2[2];
#pragma unroll
        for (int nt = 0; nt < 2; ++nt) acc2[nt] = (f32x4){0.f, 0.f, 0.f, 0.f};
#pragma unroll
        for (int ks = 0; ks < 2; ++ks) {
            f16x8 af = *(const f16x8*)&E2[(16 * w + l15) * 80 + ks * 32 + g * 8];
#pragma unroll
            for (int nt = 0; nt < 2; ++nt)
                acc2[nt] = __builtin_amdgcn_mfma_f32_16x16x32_f16(af, bw2[ks][nt], acc2[nt], 0, 0, 0);
        }

        // ---- epilogue 2: E3 = relu(C2*s2+c2); accumulate rows != p ----
#pragma unroll
        for (int nt = 0; nt < 2; ++nt)
#pragma unroll
            for (int r = 0; r < 4; ++r) {
                int a = chunk * 64 + 16 * w + 4 * g + r;
                float v = fmaxf(acc2[nt][r] * s2v[nt] + c2v[nt], 0.f);
                if (a != p) { if (nt == 0) sum0 += v; else sum1 += v; }
            }
        __syncthreads();   // protects E1/E2 reuse next chunk
    }

    // ---- reduce 32-col sums across g and waves ----
    sum0 += __shfl_xor(sum0, 16, 64);
    sum0 += __shfl_xor(sum0, 32, 64);
    sum1 += __shfl_xor(sum1, 16, 64);
    sum1 += __shfl_xor(sum1, 32, 64);
    if (lane < 16) {
        red[w * 32 + l15]      = sum0;
        red[w * 32 + 16 + l15] = sum1;
    }
    if (tid < NF) hbuf[tid] = x[(b * NF + tid) * NP + p];
    __syncthreads();
    if (tid < 32) hbuf[NF + tid] = red[tid] + red[32 + tid] + red[64 + tid] + red[96 + tid];
    __syncthreads();

    // ---- fused fo MLP (wave 0) ----
    if (tid < 64) {
        float a = 0.f;
#pragma unroll 8
        for (int k = 0; k < 48; ++k) a += hbuf[k] * fo0w[k * 64 + tid];
        h2[tid] = fmaxf(a * cs[384 + tid] + cs[448 + tid], 0.f);
    }
    __syncthreads();
    if (tid < 32) {
        float a2 = 0.f;
#pragma unroll 8
        for (int k = 0; k < 64; ++k) a2 += h2[k] * fo1w[k * 32 + tid];
        fo_out[(size_t)blk * 32 + tid] = fmaxf(a2 * cs[512 + tid] + cs[544 + tid], 0.f);
    }
}

// ---------------- deterministic sum over nodes ----------------
__global__ void reduce_kernel(const float* __restrict__ fo_out, float* __restrict__ out) {
    int b = blockIdx.x;              // 64 blocks
    int t = threadIdx.x;             // 256
    int m = t & 31;
    int g = t >> 5;                  // 8 groups
    float v = 0.f;
    for (int p = g; p < NP; p += 8) v += fo_out[(b * NP + p) * 32 + m];
    __shared__ float red[256];
    red[t] = v;
    __syncthreads();
    for (int s = 4; s >= 1; s >>= 1) {
        if (g < s) red[t] += red[t + s * 32];
        __syncthreads();
    }
    if (g == 0) out[b * 32 + m] = red[t];
}

extern "C" void kernel_launch(void* const* d_in, const int* in_sizes, int n_in,
                              void* d_out, int out_size, void* d_ws, size_t ws_size,
                              hipStream_t stream) {
    (void)in_sizes; (void)n_in; (void)out_size; (void)ws_size;
    const float* x    = (const float*)d_in[0];
    const float* fr0w = (const float*)d_in[1];
    const float* fr1w = (const float*)d_in[7];
    const float* fr2w = (const float*)d_in[13];
    const float* fo0w = (const float*)d_in[19];
    const float* fo1w = (const float*)d_in[25];

    float* ws = (float*)d_ws;
    float*    cs     = ws;                               // 1024 f32
    _Float16* Rch    = (_Float16*)(ws + 1024);           // B*P*96 fp16 = 393216 f32
    _Float16* Sch    = (_Float16*)(ws + 1024 + 393216);
    _Float16* w1f    = (_Float16*)(ws + 1024 + 2 * 393216);          // 6144 fp16
    _Float16* w2f    = (_Float16*)(ws + 1024 + 2 * 393216 + 3072);   // 2048 fp16
    float*    fo_out = ws + 1024 + 2 * 393216 + 4096;    // B*P*32 f32
    float*    out    = (float*)d_out;

    prep_kernel<<<33, 256, 0, stream>>>(fr1w, fr2w, w1f, w2f, cs,
        (const float*)d_in[2],  (const float*)d_in[3],  (const float*)d_in[4],
        (const float*)d_in[5],  (const float*)d_in[6],
        (const float*)d_in[8],  (const float*)d_in[9],  (const float*)d_in[10],
        (const float*)d_in[11], (const float*)d_in[12],
        (const float*)d_in[14], (const float*)d_in[15], (const float*)d_in[16],
        (const float*)d_in[17], (const float*)d_in[18],
        (const float*)d_in[20], (const float*)d_in[21], (const float*)d_in[22],
        (const float*)d_in[23], (const float*)d_in[24],
        (const float*)d_in[26], (const float*)d_in[27], (const float*)d_in[28],
        (const float*)d_in[29], (const float*)d_in[30]);

    rs_kernel<<<(NB * NP * 48 + 255) / 256, 256, 0, stream>>>(x, fr0w, cs, Rch, Sch);

    edge_mlp_mfma<<<NB * NP, 256, 0, stream>>>(Rch, Sch, w1f, w2f, cs,
                                               x, fo0w, fo1w, fo_out);

    reduce_kernel<<<NB, 256, 0, stream>>>(fo_out, out);
}

// Round 4
// 57.535 us; speedup vs baseline: 1.5999x; 1.5999x over previous
//
#include <hip/hip_runtime.h>

// GraphEmbeddings interaction network — zero-barrier fp16 MFMA version.
// B=64, P=128, F=16. One WAVE per (b, receiver p): builds A-fragments of
// E1 = relu(Rc[p] + Sc[a]) directly from global (no LDS), fr1/fr2 via
// mfma_f32_16x16x32_f16, E2 transposed through a wave-private LDS region,
// fo MLP fused as a per-wave tail. No __syncthreads anywhere in the hot kernel.

#define NB 64
#define NF 16
#define NP 128

typedef _Float16 f16x8 __attribute__((ext_vector_type(8)));
typedef _Float16 f16x2 __attribute__((ext_vector_type(2)));
typedef float    f32x4 __attribute__((ext_vector_type(4)));

#define LGKM0() asm volatile("s_waitcnt lgkmcnt(0)" ::: "memory"); \
                __builtin_amdgcn_sched_barrier(0)

// ---------------- fused rs + BN-fold + weight-pack kernel ----------------
// blocks 0..1535: Rc/Sc per-node partials (BN0 folded inline)
// block 1536: fold BN consts for layers fr1, fr2, fo0, fo1 into cs
// blocks 1537..1568: pack W1/W2 into MFMA B-fragment layout (fp16)
__global__ void rs_prep_kernel(const float* __restrict__ x, const float* __restrict__ w0,
                               const float* __restrict__ w1, const float* __restrict__ w2,
                               _Float16* __restrict__ w1f, _Float16* __restrict__ w2f,
                               float* __restrict__ cs,
                               _Float16* __restrict__ Rch, _Float16* __restrict__ Sch,
    const float* b0, const float* g0, const float* be0, const float* m0, const float* v0,
    const float* b1, const float* g1, const float* be1, const float* m1, const float* v1,
    const float* b2, const float* g2, const float* be2, const float* m2, const float* v2,
    const float* b3, const float* g3, const float* be3, const float* m3, const float* v3,
    const float* b4, const float* g4, const float* be4, const float* m4, const float* v4)
{
    const int bi = blockIdx.x;
    const int t = threadIdx.x;
    if (bi < 1536) {
        int idx = bi * 256 + t;            // B*P*48 (2 ch per thread)
        int c2 = idx % 48;
        int node = idx / 48;
        int p = node & (NP - 1);
        int b = node >> 7;
        int ch0 = c2 * 2, ch1 = c2 * 2 + 1;
        // inline BN0 fold (L1-hot small vectors)
        float sa = g0[ch0] * rsqrtf(v0[ch0] + 1e-3f);
        float sb = g0[ch1] * rsqrtf(v0[ch1] + 1e-3f);
        float ca = (b0[ch0] - m0[ch0]) * sa + be0[ch0];
        float cb = (b0[ch1] - m0[ch1]) * sb + be0[ch1];
        const float* xb = x + b * NF * NP + p;
        float r0 = 0.f, r1 = 0.f, s0 = 0.f, s1 = 0.f;
#pragma unroll
        for (int f = 0; f < NF; ++f) {
            float xv = xb[f * NP];
            float2 wr = *(const float2*)&w0[f * 96 + ch0];
            float2 ws = *(const float2*)&w0[(NF + f) * 96 + ch0];
            r0 += xv * wr.x; r1 += xv * wr.y;
            s0 += xv * ws.x; s1 += xv * ws.y;
        }
        f16x2 rv; rv[0] = (_Float16)(r0 * sa + ca); rv[1] = (_Float16)(r1 * sb + cb);
        f16x2 sv; sv[0] = (_Float16)(s0 * sa);      sv[1] = (_Float16)(s1 * sb);
        *(f16x2*)&Rch[idx * 2] = rv;
        *(f16x2*)&Sch[idx * 2] = sv;
    } else if (bi == 1536) {
        if (t < 64) {
            float s = g1[t] * rsqrtf(v1[t] + 1e-3f);
            cs[192 + t] = s; cs[256 + t] = (b1[t] - m1[t]) * s + be1[t];
        }
        if (t < 32) {
            float s = g2[t] * rsqrtf(v2[t] + 1e-3f);
            cs[320 + t] = s; cs[352 + t] = (b2[t] - m2[t]) * s + be2[t];
        }
        if (t < 64) {
            float s = g3[t] * rsqrtf(v3[t] + 1e-3f);
            cs[384 + t] = s; cs[448 + t] = (b3[t] - m3[t]) * s + be3[t];
        }
        if (t < 32) {
            float s = g4[t] * rsqrtf(v4[t] + 1e-3f);
            cs[512 + t] = s; cs[544 + t] = (b4[t] - m4[t]) * s + be4[t];
        }
    } else {
        int i = (bi - 1537) * 256 + t;        // 0..8191
        if (i < 6144) {                       // w1f[kb][n][j] = W1[kb*8+j][n]
            int j = i & 7, n = (i >> 3) & 63, kb = i >> 9;
            w1f[i] = (_Float16)w1[(kb * 8 + j) * 64 + n];
        } else {                              // w2f[kb][n][j] = W2[kb*8+j][n]
            int i2 = i - 6144;
            int j = i2 & 7, n = (i2 >> 3) & 31, kb = i2 >> 8;
            w2f[i2] = (_Float16)w2[(kb * 8 + j) * 32 + n];
        }
    }
}

// ---------------- edge MLP + fo, one wave per receiver, zero barriers -------
// Grid: 64 b x 32 groups = 2048 blocks, 256 threads = 4 waves = 4 receivers.
__global__ __launch_bounds__(256) void edge_fused(
    const _Float16* __restrict__ Rch, const _Float16* __restrict__ Sch,
    const _Float16* __restrict__ w1f, const _Float16* __restrict__ w2f,
    const float* __restrict__ cs, const float* __restrict__ x,
    const float* __restrict__ fo0w, const float* __restrict__ fo1w,
    float* __restrict__ fo_out)
{
    __shared__ _Float16 E2[4][32 * 72];   // wave-private: 32 rows, stride 72 (2-way free)
    __shared__ float    HW[4][116];       // wave-private: h[48] + h2[64]

    const int tid  = threadIdx.x;
    const int w    = tid >> 6;
    const int lane = tid & 63;
    const int g    = lane >> 4;
    const int l15  = lane & 15;
    const int blk  = blockIdx.x;
    const int b    = blk >> 5;
    const int p    = (blk & 31) * 4 + w;

    // --- B-fragments of W1/W2 and Rc fragment, all in registers ---
    const f16x8* W1v = (const f16x8*)w1f;
    const f16x8* W2v = (const f16x8*)w2f;
    f16x8 bw1[3][4];
#pragma unroll
    for (int ks = 0; ks < 3; ++ks)
#pragma unroll
        for (int nt = 0; nt < 4; ++nt)
            bw1[ks][nt] = W1v[(ks * 4 + g) * 64 + nt * 16 + l15];
    f16x8 bw2[2][2];
#pragma unroll
    for (int ks = 0; ks < 2; ++ks)
#pragma unroll
        for (int nt = 0; nt < 2; ++nt)
            bw2[ks][nt] = W2v[(ks * 4 + g) * 32 + nt * 16 + l15];
    f16x8 rc[3];
#pragma unroll
    for (int ks = 0; ks < 3; ++ks)
        rc[ks] = *(const f16x8*)&Rch[(size_t)(b * NP + p) * 96 + ks * 32 + g * 8];

    float s1v[4], c1v[4];
#pragma unroll
    for (int nt = 0; nt < 4; ++nt) {
        s1v[nt] = cs[192 + nt * 16 + l15];
        c1v[nt] = cs[256 + nt * 16 + l15];
    }
    float s2v[2], c2v[2];
#pragma unroll
    for (int nt = 0; nt < 2; ++nt) {
        s2v[nt] = cs[320 + nt * 16 + l15];
        c2v[nt] = cs[352 + nt * 16 + l15];
    }

    const _Float16* Sb = Sch + (size_t)b * NP * 96;
    _Float16* E2w = &E2[w][0];
    float sums[2] = {0.f, 0.f};

    for (int chunk = 0; chunk < 4; ++chunk) {
        // ---- fr1: build A-frags straight from global, MFMA ----
        f32x4 acc[2][4];
#pragma unroll
        for (int mt = 0; mt < 2; ++mt)
#pragma unroll
            for (int nt = 0; nt < 4; ++nt) acc[mt][nt] = (f32x4){0.f, 0.f, 0.f, 0.f};
#pragma unroll
        for (int mt = 0; mt < 2; ++mt) {
            int row = chunk * 32 + mt * 16 + l15;
#pragma unroll
            for (int ks = 0; ks < 3; ++ks) {
                f16x8 sv = *(const f16x8*)&Sb[row * 96 + ks * 32 + g * 8];
                f16x8 av = sv + rc[ks];
                f16x8 zz = {};
                av = __builtin_elementwise_max(av, zz);
#pragma unroll
                for (int nt = 0; nt < 4; ++nt)
                    acc[mt][nt] = __builtin_amdgcn_mfma_f32_16x16x32_f16(av, bw1[ks][nt], acc[mt][nt], 0, 0, 0);
            }
        }

        // ---- epilogue 1: E2 = relu(C1*s1+c1) -> fp16, wave-private LDS ----
#pragma unroll
        for (int mt = 0; mt < 2; ++mt)
#pragma unroll
            for (int nt = 0; nt < 4; ++nt)
#pragma unroll
                for (int r = 0; r < 4; ++r)
                    E2w[(mt * 16 + 4 * g + r) * 72 + nt * 16 + l15] =
                        (_Float16)fmaxf(acc[mt][nt][r] * s1v[nt] + c1v[nt], 0.f);
        LGKM0();   // same-wave DS ordering: writes complete before reads

        // ---- fr2 ----
        f32x4 acc2[2][2];
#pragma unroll
        for (int mt = 0; mt < 2; ++mt)
#pragma unroll
            for (int nt = 0; nt < 2; ++nt) acc2[mt][nt] = (f32x4){0.f, 0.f, 0.f, 0.f};
#pragma unroll
        for (int mt = 0; mt < 2; ++mt)
#pragma unroll
            for (int ks = 0; ks < 2; ++ks) {
                f16x8 af = *(const f16x8*)&E2w[(mt * 16 + l15) * 72 + ks * 32 + g * 8];
#pragma unroll
                for (int nt = 0; nt < 2; ++nt)
                    acc2[mt][nt] = __builtin_amdgcn_mfma_f32_16x16x32_f16(af, bw2[ks][nt], acc2[mt][nt], 0, 0, 0);
            }

        // ---- epilogue 2: relu(C2*s2+c2), accumulate senders != p ----
#pragma unroll
        for (int mt = 0; mt < 2; ++mt)
#pragma unroll
            for (int nt = 0; nt < 2; ++nt)
#pragma unroll
                for (int r = 0; r < 4; ++r) {
                    int a = chunk * 32 + mt * 16 + 4 * g + r;
                    float v = fmaxf(acc2[mt][nt][r] * s2v[nt] + c2v[nt], 0.f);
                    if (a != p) sums[nt] += v;
                }
    }

    // ---- reduce over g (lanes l15, l15+16, +32, +48) ----
#pragma unroll
    for (int nt = 0; nt < 2; ++nt) {
        sums[nt] += __shfl_xor(sums[nt], 16, 64);
        sums[nt] += __shfl_xor(sums[nt], 32, 64);
    }

    // ---- fused fo MLP, wave-private ----
    float* hw = &HW[w][0];
    if (lane < 16) {
        hw[16 + l15] = sums[0];
        hw[32 + l15] = sums[1];
    } else if (lane < 32) {
        hw[lane - 16] = x[(b * NF + (lane - 16)) * NP + p];
    }
    LGKM0();

    float a1 = 0.f;
#pragma unroll 8
    for (int k = 0; k < 48; ++k) a1 += hw[k] * fo0w[k * 64 + lane];
    hw[48 + lane] = fmaxf(a1 * cs[384 + lane] + cs[448 + lane], 0.f);
    LGKM0();

    if (lane < 32) {
        float a2 = 0.f;
#pragma unroll 8
        for (int k = 0; k < 64; ++k) a2 += hw[48 + k] * fo1w[k * 32 + lane];
        fo_out[(size_t)(b * NP + p) * 32 + lane] =
            fmaxf(a2 * cs[512 + lane] + cs[544 + lane], 0.f);
    }
}

// ---------------- deterministic sum over nodes ----------------
__global__ void reduce_kernel(const float* __restrict__ fo_out, float* __restrict__ out) {
    int b = blockIdx.x;              // 64 blocks
    int t = threadIdx.x;             // 256
    int m = t & 31;
    int g = t >> 5;                  // 8 groups
    float v = 0.f;
    for (int p = g; p < NP; p += 8) v += fo_out[(b * NP + p) * 32 + m];
    __shared__ float red[256];
    red[t] = v;
    __syncthreads();
    for (int s = 4; s >= 1; s >>= 1) {
        if (g < s) red[t] += red[t + s * 32];
        __syncthreads();
    }
    if (g == 0) out[b * 32 + m] = red[t];
}

extern "C" void kernel_launch(void* const* d_in, const int* in_sizes, int n_in,
                              void* d_out, int out_size, void* d_ws, size_t ws_size,
                              hipStream_t stream) {
    (void)in_sizes; (void)n_in; (void)out_size; (void)ws_size;
    const float* x    = (const float*)d_in[0];
    const float* fr0w = (const float*)d_in[1];
    const float* fr1w = (const float*)d_in[7];
    const float* fr2w = (const float*)d_in[13];
    const float* fo0w = (const float*)d_in[19];
    const float* fo1w = (const float*)d_in[25];

    float* ws = (float*)d_ws;
    float*    cs     = ws;                               // 1024 f32
    _Float16* Rch    = (_Float16*)(ws + 1024);           // B*P*96 fp16
    _Float16* Sch    = (_Float16*)(ws + 1024 + 393216);
    _Float16* w1f    = (_Float16*)(ws + 1024 + 2 * 393216);          // 6144 fp16
    _Float16* w2f    = (_Float16*)(ws + 1024 + 2 * 393216 + 3072);   // 2048 fp16
    float*    fo_out = ws + 1024 + 2 * 393216 + 4096;    // B*P*32 f32
    float*    out    = (float*)d_out;

    rs_prep_kernel<<<1569, 256, 0, stream>>>(x, fr0w, fr1w, fr2w, w1f, w2f, cs, Rch, Sch,
        (const float*)d_in[2],  (const float*)d_in[3],  (const float*)d_in[4],
        (const float*)d_in[5],  (const float*)d_in[6],
        (const float*)d_in[8],  (const float*)d_in[9],  (const float*)d_in[10],
        (const float*)d_in[11], (const float*)d_in[12],
        (const float*)d_in[14], (const float*)d_in[15], (const float*)d_in[16],
        (const float*)d_in[17], (const float*)d_in[18],
        (const float*)d_in[20], (const float*)d_in[21], (const float*)d_in[22],
        (const float*)d_in[23], (const float*)d_in[24],
        (const float*)d_in[26], (const float*)d_in[27], (const float*)d_in[28],
        (const float*)d_in[29], (const float*)d_in[30]);

    edge_fused<<<NB * 32, 256, 0, stream>>>(Rch, Sch, w1f, w2f, cs, x, fo0w, fo1w, fo_out);

    reduce_kernel<<<NB, 256, 0, stream>>>(fo_out, out);
}